// Round 4
// baseline (120.699 us; speedup 1.0000x reference)
//
#include <hip/hip_runtime.h>
#include <math.h>

// ---------------------------------------------------------------------------
// AUV Fossen 6-DOF RK2 step, K independent 13-float states.
// R4: within-wave 2-deep pipeline (counted vmcnt, T3/T14 pattern). Each block
// = 512 rows = 2 tiles; each wave owns 64 rows of each tile end-to-end, no
// block barriers. ALL staging (x and u) via ordered global_load_lds issued
// up-front: [xA(4), uA(2), xB(4), uB(2)]. s_waitcnt vmcnt(6) -> tile A ready
// (B's 6 still in flight, HBM latency hides under A's compute);
// after A's 4 stores, s_waitcnt vmcnt(4) -> B ready (A's stores in flight).
// vmcnt(N) drains oldest-first, so stray uniform loads issued between the
// DMAs and the wait can only make the wait stricter, never unsafe.
// Grid 1024 blocks x 39.7KB LDS = exactly 4 blocks/CU, all resident.
// History: R2 (256,8) forced 32 VGPR -> 300MB spill traffic, 103us. (256,4)
// + 64 VGPR is the proven no-spill point. R1 lockstep barriers: 42.7us at
// occ 31%, hbm 1.85 TB/s. Floor: ~67MB traffic -> ~11us @6.3TB/s.
// ---------------------------------------------------------------------------

__device__ __forceinline__ float fast_rcp(float x) {
    float r = __builtin_amdgcn_rcpf(x);
    return r * (2.0f - x * r);        // 1 Newton step
}

__device__ __forceinline__ void fossen_dot(const float* __restrict__ X,
                                           const float* __restrict__ U,
                                           const float* __restrict__ smi,  // LDS [6][8] padded, broadcast
                                           const float* __restrict__ mTot, // uniform -> s_load
                                           const float* __restrict__ linDamp,
                                           const float* __restrict__ linDampFow,
                                           const float* __restrict__ qdiag,  // sgpr [6]
                                           const float* __restrict__ lddiag, // sgpr [6]
                                           const float* __restrict__ cgcb,   // sgpr [6]
                                           float fgz, float fbz,
                                           bool ldDiag, bool ldfZero,
                                           float* __restrict__ xd)
{
    const float qx = X[3], qy = X[4], qz = X[5], qw = X[6];
    const float r00 = 1.f - 2.f*(qy*qy + qz*qz);
    const float r01 = 2.f*(qx*qy - qz*qw);
    const float r02 = 2.f*(qx*qz + qy*qw);
    const float r10 = 2.f*(qx*qy + qz*qw);
    const float r11 = 1.f - 2.f*(qx*qx + qz*qz);
    const float r12 = 2.f*(qy*qz - qx*qw);
    const float r20 = 2.f*(qx*qz - qy*qw);
    const float r21 = 2.f*(qy*qz + qx*qw);
    const float r22 = 1.f - 2.f*(qx*qx + qy*qy);

    const float v0 = X[7],  v1 = X[8],  v2 = X[9];
    const float v3 = X[10], v4 = X[11], v5 = X[12];

    xd[0] = r00*v0 + r01*v1 + r02*v2;
    xd[1] = r10*v0 + r11*v1 + r12*v2;
    xd[2] = r20*v0 + r21*v1 + r22*v2;
    xd[3] = 0.5f*(-qx*v3 - qy*v4 - qz*v5);
    xd[4] = 0.5f*( qw*v3 - qz*v4 + qy*v5);
    xd[5] = 0.5f*( qz*v3 + qw*v4 - qx*v5);
    xd[6] = 0.5f*(-qy*v3 + qx*v4 + qw*v5);

    const float v[6] = {v0, v1, v2, v3, v4, v5};

    // P = -Dv. Fast path: diagonal linDamp + zero linDampFow (uniform flags).
    float P[6];
#pragma unroll
    for (int i = 0; i < 6; ++i)
        P[i] = lddiag[i]*v[i] + qdiag[i]*fabsf(v[i])*v[i];
    if (!ldDiag) {
#pragma unroll
        for (int i = 0; i < 6; ++i) {
            float ld = 0.f;
#pragma unroll
            for (int j = 0; j < 6; ++j)
                if (j != i) ld += linDamp[i*6 + j] * v[j];
            P[i] += ld;
        }
    }
    if (!ldfZero) {
#pragma unroll
        for (int i = 0; i < 6; ++i) {
            float ldf = 0.f;
#pragma unroll
            for (int j = 0; j < 6; ++j) ldf += linDampFow[i*6 + j] * v[j];
            P[i] += v[i]*ldf;
        }
    }

    // Coriolis via mv = M v, then cross products (skew(a)b = a x b)
    float mv[6];
#pragma unroll
    for (int i = 0; i < 6; ++i) {
        float s = 0.f;
#pragma unroll
        for (int j = 0; j < 6; ++j) s += mTot[i*6 + j] * v[j];
        mv[i] = s;
    }
    float Cv[6];
    Cv[0] = -(mv[1]*v5 - mv[2]*v4);
    Cv[1] = -(mv[2]*v3 - mv[0]*v5);
    Cv[2] = -(mv[0]*v4 - mv[1]*v3);
    Cv[3] = -(mv[1]*v2 - mv[2]*v1) - (mv[4]*v5 - mv[5]*v4);
    Cv[4] = -(mv[2]*v0 - mv[0]*v2) - (mv[5]*v3 - mv[3]*v5);
    Cv[5] = -(mv[0]*v1 - mv[1]*v0) - (mv[3]*v4 - mv[4]*v3);

    // restoring (only row 2 of rot enters)
    const float fb0 = r20*fgz, fb1 = r21*fgz, fb2 = r22*fgz;
    const float bb0 = r20*fbz, bb1 = r21*fbz, bb2 = r22*fbz;
    const float cgx = cgcb[0], cgy = cgcb[1], cgz = cgcb[2];
    const float cbx = cgcb[3], cby = cgcb[4], cbz = cgcb[5];
    const float m0 = cgy*fb2 - cgz*fb1 + cby*bb2 - cbz*bb1;
    const float m1 = cgz*fb0 - cgx*fb2 + cbz*bb0 - cbx*bb2;
    const float m2 = cgx*fb1 - cgy*fb0 + cbx*bb1 - cby*bb0;
    const float g[6] = { -(fb0+bb0), -(fb1+bb1), -(fb2+bb2), -m0, -m1, -m2 };

    float rhs[6];
#pragma unroll
    for (int i = 0; i < 6; ++i) rhs[i] = U[i] - Cv[i] + P[i] - g[i];

    // vDot = Minv @ rhs  (rows broadcast from LDS as b128+b64, die after use)
#pragma unroll
    for (int i = 0; i < 6; ++i) {
        const float4 m4 = *(const float4*)(&smi[i*8]);
        const float2 m2 = *(const float2*)(&smi[i*8 + 4]);
        xd[7+i] = m4.x*rhs[0] + m4.y*rhs[1] + m4.z*rhs[2] + m4.w*rhs[3]
                + m2.x*rhs[4] + m2.y*rhs[5];
    }
}

// lane-0 Gauss-Jordan (static-index, no pivot; mTot diag-dominant, validated
// vs reference) into this wave's padded smi region.
__device__ __forceinline__ void gj_inverse_to_lds(const float* __restrict__ mTot,
                                                  float* __restrict__ smiw)
{
    float a[36], Mi[36];
#pragma unroll
    for (int i = 0; i < 36; ++i) a[i] = mTot[i];
#pragma unroll
    for (int i = 0; i < 36; ++i) Mi[i] = 0.f;
#pragma unroll
    for (int i = 0; i < 6; ++i) Mi[i*6 + i] = 1.f;
#pragma unroll
    for (int col = 0; col < 6; ++col) {
        const float d = fast_rcp(a[col*6 + col]);
#pragma unroll
        for (int j = 0; j < 6; ++j) { a[col*6+j] *= d; Mi[col*6+j] *= d; }
#pragma unroll
        for (int r = 0; r < 6; ++r) {
            if (r == col) continue;
            const float f = a[r*6 + col];
#pragma unroll
            for (int j = 0; j < 6; ++j) {
                a[r*6+j]  -= f * a[col*6+j];
                Mi[r*6+j] -= f * Mi[col*6+j];
            }
        }
    }
#pragma unroll
    for (int r = 0; r < 6; ++r)
#pragma unroll
        for (int c = 0; c < 6; ++c) smiw[r*8 + c] = Mi[r*6 + c];
}

__global__ void __launch_bounds__(256, 4)
auv_rk2_fused(const float* __restrict__ x, const float* __restrict__ u,
              const float* __restrict__ mass, const float* __restrict__ volume,
              const float* __restrict__ cog, const float* __restrict__ cob,
              const float* __restrict__ mTot, const float* __restrict__ linDamp,
              const float* __restrict__ linDampFow,
              const float* __restrict__ quadDamp,
              float* __restrict__ out, int K)
{
    __shared__ float sx[512 * 13];     // 26624 B: two 256-row tiles, packed
    __shared__ float su[512 * 6];      // 12288 B: two 256-row u tiles
    __shared__ float smi[4][48];       // per-WAVE inv(mTot), rows padded to 8
    const int tid   = threadIdx.x;
    const int w     = tid >> 6;        // wave id (0..3)
    const int l     = tid & 63;        // lane id
    const int base  = blockIdx.x * 512;
    const int nElem = min(512, K - base);

    // ---- uniform constants + structure flags (s_load/SALU) ----
    float qdiag[6], lddiag[6], cgcb[6];
#pragma unroll
    for (int i = 0; i < 6; ++i) { qdiag[i] = quadDamp[i*6+i]; lddiag[i] = linDamp[i*6+i]; }
#pragma unroll
    for (int i = 0; i < 3; ++i) { cgcb[i] = cog[i]; cgcb[3+i] = cob[i]; }
    const float fgz = -mass[0] * 9.81f;
    const float fbz =  volume[0] * 1028.0f * 9.81f;

    bool ldDiag = true, ldfZero = true;
#pragma unroll
    for (int i = 0; i < 6; ++i)
#pragma unroll
        for (int j = 0; j < 6; ++j) {
            ldfZero = ldfZero && (linDampFow[i*6+j] == 0.0f);
            if (i != j) ldDiag = ldDiag && (linDamp[i*6+j] == 0.0f);
        }

    if (nElem == 512) {
        // ========== wave-independent 2-deep pipeline, NO barriers ==========
        const float* gx = x + (size_t)base * 13;
        const float* gu = u + (size_t)base * 6;

        // Issue ALL DMA in pinned order: per tile t: x(4 issues) + u(2 issues).
        // Wave w's x slice of tile t: float4 [t*832 + w*208, +208);
        // u slice: float4 [t*384 + w*96, +96).
#pragma unroll
        for (int t = 0; t < 2; ++t) {
            const int xb = t*832 + w*208;
#pragma unroll
            for (int it = 0; it < 3; ++it) {
                const int k = xb + it*64 + l;
                __builtin_amdgcn_global_load_lds(
                    (const __attribute__((address_space(1))) void*)(gx + (size_t)k*4),
                    (__attribute__((address_space(3))) void*)(&sx[k*4]), 16, 0, 0);
            }
            if (l < 16) {
                const int k = xb + 192 + l;
                __builtin_amdgcn_global_load_lds(
                    (const __attribute__((address_space(1))) void*)(gx + (size_t)k*4),
                    (__attribute__((address_space(3))) void*)(&sx[k*4]), 16, 0, 0);
            }
            const int ub = t*384 + w*96;
            {
                const int k = ub + l;
                __builtin_amdgcn_global_load_lds(
                    (const __attribute__((address_space(1))) void*)(gu + (size_t)k*4),
                    (__attribute__((address_space(3))) void*)(&su[k*4]), 16, 0, 0);
            }
            if (l < 32) {
                const int k = ub + 64 + l;
                __builtin_amdgcn_global_load_lds(
                    (const __attribute__((address_space(1))) void*)(gu + (size_t)k*4),
                    (__attribute__((address_space(3))) void*)(&su[k*4]), 16, 0, 0);
            }
        }

        // per-wave lane-0 inverse into smi[w]: overlaps the in-flight DMA.
        if (l == 0) gj_inverse_to_lds(mTot, &smi[w][0]);

        float4*       go = (float4*)(out + (size_t)base * 13);
        const float4* s4 = (const float4*)sx;

#pragma unroll
        for (int t = 0; t < 2; ++t) {
            if (t == 0) {
                // drain oldest 6 (= tile0 x+u) + GJ ds_writes; tile1's 6 stay
                // in flight under tile0's compute.
                asm volatile("s_waitcnt vmcnt(6) lgkmcnt(0)" ::: "memory");
            } else {
                // drain tile1 DMA; tile0's 4 stores (issued last) stay in flight.
                asm volatile("s_waitcnt vmcnt(4)" ::: "memory");
            }
            __builtin_amdgcn_sched_barrier(0);

            const int rowf = t*3328 + tid*13;
            const int uf   = t*1536 + tid*6;
            float X[13], U[6];
#pragma unroll
            for (int j = 0; j < 13; ++j) X[j] = sx[rowf + j];
#pragma unroll
            for (int j = 0; j < 6; ++j)  U[j] = su[uf + j];

            float k1[13], X2[13], k2[13], Y[13];
            fossen_dot(X, U, &smi[w][0], mTot, linDamp, linDampFow, qdiag,
                       lddiag, cgcb, fgz, fbz, ldDiag, ldfZero, k1);
#pragma unroll
            for (int j = 0; j < 13; ++j) X2[j] = X[j] + 0.1f * k1[j];
            fossen_dot(X2, U, &smi[w][0], mTot, linDamp, linDampFow, qdiag,
                       lddiag, cgcb, fgz, fbz, ldDiag, ldfZero, k2);
#pragma unroll
            for (int j = 0; j < 13; ++j) Y[j] = X[j] + 0.05f * (k1[j] + k2[j]);

            const float nq  = Y[3]*Y[3] + Y[4]*Y[4] + Y[5]*Y[5] + Y[6]*Y[6];
            float inv = __builtin_amdgcn_rsqf(nq);
            inv = inv * (1.5f - 0.5f * nq * inv * inv);   // 1 NR step
            Y[3] *= inv; Y[4] *= inv; Y[5] *= inv; Y[6] *= inv;

            // own-row repack (overwrites own input region), wave-local drain,
            // coalesced float4 store of this wave's slice.
#pragma unroll
            for (int j = 0; j < 13; ++j) sx[rowf + j] = Y[j];

            asm volatile("s_waitcnt lgkmcnt(0)" ::: "memory");
            __builtin_amdgcn_sched_barrier(0);

            const int xb = t*832 + w*208;
#pragma unroll
            for (int it = 0; it < 3; ++it) {
                const int k = xb + it*64 + l;
                go[k] = s4[k];
            }
            if (l < 16) {
                const int k = xb + 192 + l;
                go[k] = s4[k];
            }
        }
    } else {
        // ========== tail path (block-uniform branch, barriers OK) ==========
        for (int k = tid; k < nElem*13; k += 256) sx[k] = x[(size_t)base*13 + k];
        if (tid == 0) gj_inverse_to_lds(mTot, &smi[0][0]);
        __syncthreads();

#pragma unroll
        for (int rr = 0; rr < 2; ++rr) {
            const int r = tid + rr*256;
            if (r < nElem) {
                float X[13], U[6];
#pragma unroll
                for (int j = 0; j < 13; ++j) X[j] = sx[r*13 + j];
                const float* gu = u + (size_t)(base + r) * 6;
#pragma unroll
                for (int j = 0; j < 6; ++j) U[j] = gu[j];

                float k1[13], X2[13], k2[13], Y[13];
                fossen_dot(X, U, &smi[0][0], mTot, linDamp, linDampFow, qdiag,
                           lddiag, cgcb, fgz, fbz, ldDiag, ldfZero, k1);
#pragma unroll
                for (int j = 0; j < 13; ++j) X2[j] = X[j] + 0.1f * k1[j];
                fossen_dot(X2, U, &smi[0][0], mTot, linDamp, linDampFow, qdiag,
                           lddiag, cgcb, fgz, fbz, ldDiag, ldfZero, k2);
#pragma unroll
                for (int j = 0; j < 13; ++j) Y[j] = X[j] + 0.05f * (k1[j] + k2[j]);

                const float nq  = Y[3]*Y[3] + Y[4]*Y[4] + Y[5]*Y[5] + Y[6]*Y[6];
                float inv = __builtin_amdgcn_rsqf(nq);
                inv = inv * (1.5f - 0.5f * nq * inv * inv);
                Y[3] *= inv; Y[4] *= inv; Y[5] *= inv; Y[6] *= inv;
#pragma unroll
                for (int j = 0; j < 13; ++j) sx[r*13 + j] = Y[j];
            }
        }
        __syncthreads();
        for (int k = tid; k < nElem*13; k += 256) out[(size_t)base*13 + k] = sx[k];
    }
}

extern "C" void kernel_launch(void* const* d_in, const int* in_sizes, int n_in,
                              void* d_out, int out_size, void* d_ws, size_t ws_size,
                              hipStream_t stream)
{
    const float* x          = (const float*)d_in[0];
    const float* u          = (const float*)d_in[1];
    const float* mass       = (const float*)d_in[2];
    const float* volume     = (const float*)d_in[3];
    const float* cog        = (const float*)d_in[4];
    const float* cob        = (const float*)d_in[5];
    const float* mTot       = (const float*)d_in[6];
    const float* linDamp    = (const float*)d_in[7];
    const float* linDampFow = (const float*)d_in[8];
    const float* quadDamp   = (const float*)d_in[9];
    float*       out        = (float*)d_out;

    const int K = in_sizes[0] / 13;
    const int blocks = (K + 511) / 512;
    auv_rk2_fused<<<blocks, 256, 0, stream>>>(x, u, mass, volume, cog, cob,
                                              mTot, linDamp, linDampFow,
                                              quadDamp, out, K);
}

// Round 5
// 116.364 us; speedup vs baseline: 1.0373x; 1.0373x over previous
//
#include <hip/hip_runtime.h>
#include <math.h>

// ---------------------------------------------------------------------------
// AUV Fossen 6-DOF RK2 step, K independent 13-float states.
// R5: pure elementwise form, maximum memory-level parallelism. Evidence:
// four structural variants (R0 lockstep, R1 barriers, R3 wave-independent
// DMA, R4 2-deep counted-vmcnt pipeline) all ~40us-class -> DMA/LDS
// choreography was never the lever. R1 counters (79MB @ 1.85TB/s, occ 31%,
// VALU 25%) say latency-bound with poor MLP: global_load_lds = only 4
// outstanding requests/wave, serial LDS round trips. R5: NO data LDS.
// Each thread loads its own 52B row direct to regs (3x 4B-aligned dwordx4
// + dword, wave-dense), computes, stores direct. 7 independent loads/thread
// = 256 outstanding reqs/wave. Zero barriers/choreography. LDS = 768B (smi)
// -> nothing blocks 8 blocks/CU; VGPR target 64-84 ((256,4) proven no-spill;
// R2 showed (256,8)->32 VGPR = 300MB spill disaster, never again).
// Floor: 67MB -> ~11us @6.3TB/s; fill-poisoned-cache floor ~2x that.
// ---------------------------------------------------------------------------

typedef float f4u __attribute__((ext_vector_type(4), aligned(4)));
typedef float f2u __attribute__((ext_vector_type(2), aligned(8)));

__device__ __forceinline__ float fast_rcp(float x) {
    float r = __builtin_amdgcn_rcpf(x);
    return r * (2.0f - x * r);        // 1 Newton step
}

__device__ __forceinline__ void fossen_dot(const float* __restrict__ X,
                                           const float* __restrict__ U,
                                           const float* __restrict__ smi,  // LDS [6][8] padded, broadcast
                                           const float* __restrict__ mTot, // uniform -> s_load
                                           const float* __restrict__ linDamp,
                                           const float* __restrict__ linDampFow,
                                           const float* __restrict__ qdiag,  // sgpr [6]
                                           const float* __restrict__ lddiag, // sgpr [6]
                                           const float* __restrict__ cgcb,   // sgpr [6]
                                           float fgz, float fbz,
                                           bool ldDiag, bool ldfZero,
                                           float* __restrict__ xd)
{
    const float qx = X[3], qy = X[4], qz = X[5], qw = X[6];
    const float r00 = 1.f - 2.f*(qy*qy + qz*qz);
    const float r01 = 2.f*(qx*qy - qz*qw);
    const float r02 = 2.f*(qx*qz + qy*qw);
    const float r10 = 2.f*(qx*qy + qz*qw);
    const float r11 = 1.f - 2.f*(qx*qx + qz*qz);
    const float r12 = 2.f*(qy*qz - qx*qw);
    const float r20 = 2.f*(qx*qz - qy*qw);
    const float r21 = 2.f*(qy*qz + qx*qw);
    const float r22 = 1.f - 2.f*(qx*qx + qy*qy);

    const float v0 = X[7],  v1 = X[8],  v2 = X[9];
    const float v3 = X[10], v4 = X[11], v5 = X[12];

    xd[0] = r00*v0 + r01*v1 + r02*v2;
    xd[1] = r10*v0 + r11*v1 + r12*v2;
    xd[2] = r20*v0 + r21*v1 + r22*v2;
    xd[3] = 0.5f*(-qx*v3 - qy*v4 - qz*v5);
    xd[4] = 0.5f*( qw*v3 - qz*v4 + qy*v5);
    xd[5] = 0.5f*( qz*v3 + qw*v4 - qx*v5);
    xd[6] = 0.5f*(-qy*v3 + qx*v4 + qw*v5);

    const float v[6] = {v0, v1, v2, v3, v4, v5};

    // P = -Dv. Fast path: diagonal linDamp + zero linDampFow (uniform flags).
    float P[6];
#pragma unroll
    for (int i = 0; i < 6; ++i)
        P[i] = lddiag[i]*v[i] + qdiag[i]*fabsf(v[i])*v[i];
    if (!ldDiag) {
#pragma unroll
        for (int i = 0; i < 6; ++i) {
            float ld = 0.f;
#pragma unroll
            for (int j = 0; j < 6; ++j)
                if (j != i) ld += linDamp[i*6 + j] * v[j];
            P[i] += ld;
        }
    }
    if (!ldfZero) {
#pragma unroll
        for (int i = 0; i < 6; ++i) {
            float ldf = 0.f;
#pragma unroll
            for (int j = 0; j < 6; ++j) ldf += linDampFow[i*6 + j] * v[j];
            P[i] += v[i]*ldf;
        }
    }

    // Coriolis via mv = M v, then cross products (skew(a)b = a x b)
    float mv[6];
#pragma unroll
    for (int i = 0; i < 6; ++i) {
        float s = 0.f;
#pragma unroll
        for (int j = 0; j < 6; ++j) s += mTot[i*6 + j] * v[j];
        mv[i] = s;
    }
    float Cv[6];
    Cv[0] = -(mv[1]*v5 - mv[2]*v4);
    Cv[1] = -(mv[2]*v3 - mv[0]*v5);
    Cv[2] = -(mv[0]*v4 - mv[1]*v3);
    Cv[3] = -(mv[1]*v2 - mv[2]*v1) - (mv[4]*v5 - mv[5]*v4);
    Cv[4] = -(mv[2]*v0 - mv[0]*v2) - (mv[5]*v3 - mv[3]*v5);
    Cv[5] = -(mv[0]*v1 - mv[1]*v0) - (mv[3]*v4 - mv[4]*v3);

    // restoring (only row 2 of rot enters)
    const float fb0 = r20*fgz, fb1 = r21*fgz, fb2 = r22*fgz;
    const float bb0 = r20*fbz, bb1 = r21*fbz, bb2 = r22*fbz;
    const float cgx = cgcb[0], cgy = cgcb[1], cgz = cgcb[2];
    const float cbx = cgcb[3], cby = cgcb[4], cbz = cgcb[5];
    const float m0 = cgy*fb2 - cgz*fb1 + cby*bb2 - cbz*bb1;
    const float m1 = cgz*fb0 - cgx*fb2 + cbz*bb0 - cbx*bb2;
    const float m2 = cgx*fb1 - cgy*fb0 + cbx*bb1 - cby*bb0;
    const float g[6] = { -(fb0+bb0), -(fb1+bb1), -(fb2+bb2), -m0, -m1, -m2 };

    float rhs[6];
#pragma unroll
    for (int i = 0; i < 6; ++i) rhs[i] = U[i] - Cv[i] + P[i] - g[i];

    // vDot = Minv @ rhs  (rows broadcast from LDS as b128+b64, die after use)
#pragma unroll
    for (int i = 0; i < 6; ++i) {
        const float4 m4 = *(const float4*)(&smi[i*8]);
        const float2 m2 = *(const float2*)(&smi[i*8 + 4]);
        xd[7+i] = m4.x*rhs[0] + m4.y*rhs[1] + m4.z*rhs[2] + m4.w*rhs[3]
                + m2.x*rhs[4] + m2.y*rhs[5];
    }
}

// lane-0 Gauss-Jordan (static-index, no pivot; mTot diag-dominant, validated
// vs reference) into this wave's padded smi region.
__device__ __forceinline__ void gj_inverse_to_lds(const float* __restrict__ mTot,
                                                  float* __restrict__ smiw)
{
    float a[36], Mi[36];
#pragma unroll
    for (int i = 0; i < 36; ++i) a[i] = mTot[i];
#pragma unroll
    for (int i = 0; i < 36; ++i) Mi[i] = 0.f;
#pragma unroll
    for (int i = 0; i < 6; ++i) Mi[i*6 + i] = 1.f;
#pragma unroll
    for (int col = 0; col < 6; ++col) {
        const float d = fast_rcp(a[col*6 + col]);
#pragma unroll
        for (int j = 0; j < 6; ++j) { a[col*6+j] *= d; Mi[col*6+j] *= d; }
#pragma unroll
        for (int r = 0; r < 6; ++r) {
            if (r == col) continue;
            const float f = a[r*6 + col];
#pragma unroll
            for (int j = 0; j < 6; ++j) {
                a[r*6+j]  -= f * a[col*6+j];
                Mi[r*6+j] -= f * Mi[col*6+j];
            }
        }
    }
#pragma unroll
    for (int r = 0; r < 6; ++r)
#pragma unroll
        for (int c = 0; c < 6; ++c) smiw[r*8 + c] = Mi[r*6 + c];
}

__global__ void __launch_bounds__(256, 4)
auv_rk2_fused(const float* __restrict__ x, const float* __restrict__ u,
              const float* __restrict__ mass, const float* __restrict__ volume,
              const float* __restrict__ cog, const float* __restrict__ cob,
              const float* __restrict__ mTot, const float* __restrict__ linDamp,
              const float* __restrict__ linDampFow,
              const float* __restrict__ quadDamp,
              float* __restrict__ out, int K)
{
    __shared__ float smi[4][48];       // per-WAVE inv(mTot), rows padded to 8
    const int tid = threadIdx.x;
    const int w   = tid >> 6;          // wave id (0..3)
    const int l   = tid & 63;          // lane id
    const int idx = blockIdx.x * 256 + tid;
    const bool live = (idx < K);

    // ---- 1) issue ALL per-thread loads first: 7 independent vector loads,
    //         wave-dense 52B/row + 24B/row regions. Max requests in flight.
    f4u xa = {0,0,0,0}, xb = {0,0,0,0}, xc = {0,0,0,0};
    float xd13 = 0.f;
    f2u ua = {0,0}, ub = {0,0}, uc = {0,0};
    if (live) {
        const float* gxr = x + (size_t)idx * 13;
        xa = *(const f4u*)(gxr);
        xb = *(const f4u*)(gxr + 4);
        xc = *(const f4u*)(gxr + 8);
        xd13 = gxr[12];
        const float* gur = u + (size_t)idx * 6;
        ua = *(const f2u*)(gur);
        ub = *(const f2u*)(gur + 2);
        uc = *(const f2u*)(gur + 4);
    }

    // ---- 2) uniform constants + structure flags (s_load/SALU, free-ish) ----
    float qdiag[6], lddiag[6], cgcb[6];
#pragma unroll
    for (int i = 0; i < 6; ++i) { qdiag[i] = quadDamp[i*6+i]; lddiag[i] = linDamp[i*6+i]; }
#pragma unroll
    for (int i = 0; i < 3; ++i) { cgcb[i] = cog[i]; cgcb[3+i] = cob[i]; }
    const float fgz = -mass[0] * 9.81f;
    const float fbz =  volume[0] * 1028.0f * 9.81f;

    bool ldDiag = true, ldfZero = true;
#pragma unroll
    for (int i = 0; i < 6; ++i)
#pragma unroll
        for (int j = 0; j < 6; ++j) {
            ldfZero = ldfZero && (linDampFow[i*6+j] == 0.0f);
            if (i != j) ldDiag = ldDiag && (linDamp[i*6+j] == 0.0f);
        }

    // ---- 3) per-wave lane-0 GJ inverse -> smi[w]; overlaps load latency.
    //         Wave-local ds_write -> ds_read: in-order per wave, drained by
    //         lgkmcnt. No block barrier anywhere in this kernel.
    if (l == 0) gj_inverse_to_lds(mTot, &smi[w][0]);
    asm volatile("s_waitcnt lgkmcnt(0)" ::: "memory");
    __builtin_amdgcn_sched_barrier(0);

    if (live) {
        float X[13], U[6];
        X[0]=xa.x;  X[1]=xa.y;  X[2]=xa.z;  X[3]=xa.w;
        X[4]=xb.x;  X[5]=xb.y;  X[6]=xb.z;  X[7]=xb.w;
        X[8]=xc.x;  X[9]=xc.y;  X[10]=xc.z; X[11]=xc.w;
        X[12]=xd13;
        U[0]=ua.x; U[1]=ua.y; U[2]=ub.x; U[3]=ub.y; U[4]=uc.x; U[5]=uc.y;

        float k1[13], X2[13], k2[13], Y[13];
        fossen_dot(X, U, &smi[w][0], mTot, linDamp, linDampFow, qdiag, lddiag,
                   cgcb, fgz, fbz, ldDiag, ldfZero, k1);
#pragma unroll
        for (int j = 0; j < 13; ++j) X2[j] = X[j] + 0.1f * k1[j];
        fossen_dot(X2, U, &smi[w][0], mTot, linDamp, linDampFow, qdiag, lddiag,
                   cgcb, fgz, fbz, ldDiag, ldfZero, k2);
#pragma unroll
        for (int j = 0; j < 13; ++j) Y[j] = X[j] + 0.05f * (k1[j] + k2[j]);

        const float nq  = Y[3]*Y[3] + Y[4]*Y[4] + Y[5]*Y[5] + Y[6]*Y[6];
        float inv = __builtin_amdgcn_rsqf(nq);
        inv = inv * (1.5f - 0.5f * nq * inv * inv);   // 1 NR step
        Y[3] *= inv; Y[4] *= inv; Y[5] *= inv; Y[6] *= inv;

        // ---- 4) direct per-thread store: 3x dwordx4 + dword, wave-dense
        //         52B/row -> L2 write-combines to full lines.
        float* gor = out + (size_t)idx * 13;
        f4u ya, yb, yc;
        ya.x=Y[0];  ya.y=Y[1];  ya.z=Y[2];  ya.w=Y[3];
        yb.x=Y[4];  yb.y=Y[5];  yb.z=Y[6];  yb.w=Y[7];
        yc.x=Y[8];  yc.y=Y[9];  yc.z=Y[10]; yc.w=Y[11];
        *(f4u*)(gor)     = ya;
        *(f4u*)(gor + 4) = yb;
        *(f4u*)(gor + 8) = yc;
        gor[12] = Y[12];
    }
}

extern "C" void kernel_launch(void* const* d_in, const int* in_sizes, int n_in,
                              void* d_out, int out_size, void* d_ws, size_t ws_size,
                              hipStream_t stream)
{
    const float* x          = (const float*)d_in[0];
    const float* u          = (const float*)d_in[1];
    const float* mass       = (const float*)d_in[2];
    const float* volume     = (const float*)d_in[3];
    const float* cog        = (const float*)d_in[4];
    const float* cob        = (const float*)d_in[5];
    const float* mTot       = (const float*)d_in[6];
    const float* linDamp    = (const float*)d_in[7];
    const float* linDampFow = (const float*)d_in[8];
    const float* quadDamp   = (const float*)d_in[9];
    float*       out        = (float*)d_out;

    const int K = in_sizes[0] / 13;
    const int blocks = (K + 255) / 256;
    auv_rk2_fused<<<blocks, 256, 0, stream>>>(x, u, mass, volume, cog, cob,
                                              mTot, linDamp, linDampFow,
                                              quadDamp, out, K);
}